// Round 7
// baseline (18241.562 us; speedup 1.0000x reference)
//
#include <hip/hip_runtime.h>
#include <hip/hip_cooperative_groups.h>
#include <cstdint>
#include <cstddef>

namespace cg = cooperative_groups;

static constexpr int Nn = 8192;   // rows of X
static constexpr int Mm = 8192;   // rows of Y
static constexpr int Kd = 256;    // feature dim
static constexpr float LAM_F   = 10.0f;
static constexpr float INV_N_F = 1.0f / 8192.0f;

typedef _Float16 h16;
typedef _Float16 h16x4 __attribute__((ext_vector_type(4)));
typedef _Float16 f16x8 __attribute__((ext_vector_type(8)));
typedef float    f32x16 __attribute__((ext_vector_type(16)));

// ---------- fp8 e4m3 helpers (HW cvt on gfx950; manual RNE fallback) ----------
__device__ __forceinline__ float dec1_fp8(uint32_t b) {      // fallback decode (positive, finite)
  uint32_t e = (b >> 3) & 15u, m = b & 7u;
  float n = __uint_as_float(((e + 120u) << 23) | (m << 20)); // normal
  float s = (float)m * 0.001953125f;                         // subnormal: m * 2^-9
  return e ? n : s;
}
__device__ __forceinline__ void cvt4_fp8(uint32_t w, float* o) {
#if __has_builtin(__builtin_amdgcn_cvt_pk_f32_fp8)
  auto lo = __builtin_amdgcn_cvt_pk_f32_fp8(w, false);
  auto hi = __builtin_amdgcn_cvt_pk_f32_fp8(w, true);
  o[0] = lo[0]; o[1] = lo[1]; o[2] = hi[0]; o[3] = hi[1];
#else
  o[0] = dec1_fp8(w & 255u); o[1] = dec1_fp8((w >> 8) & 255u);
  o[2] = dec1_fp8((w >> 16) & 255u); o[3] = dec1_fp8(w >> 24);
#endif
}
__device__ __forceinline__ uint8_t enc1_fp8(float x) {       // x in (0,1]
#if __has_builtin(__builtin_amdgcn_cvt_pk_fp8_f32)
  return (uint8_t)(__builtin_amdgcn_cvt_pk_fp8_f32(x, x, 0, false) & 0xff);
#else
  uint32_t b = __float_as_uint(x);
  int e = (int)((b >> 23) & 255) - 127;
  uint32_t m = b & 0x7fffffu;
  if (e < -9) return 0;
  if (e >= -6) {                                             // normal, RNE on 3-bit mantissa
    uint32_t keep = m >> 20, rest = m & 0xfffffu;
    if (rest > 0x80000u || (rest == 0x80000u && (keep & 1u))) keep++;
    return (uint8_t)(((uint32_t)(e + 7) << 3) + keep);       // carry rolls into exponent
  }
  return (uint8_t)(int)(x * 512.0f + 0.5f);                  // subnormal
#endif
}

// ---------- staging slot swizzle (conflict-free ds_write/ds_read) ----------
__device__ __forceinline__ int frag_slot(int t, int s, int l) {
  return (t * 4 + s) * 64 + (l & 32) + ((l & 31) ^ (2 * s + (l >> 5)));
}

// ---------- load helpers for fp32 fallback path ----------
__device__ __forceinline__ void load8(const float* p, float* o) {
#pragma unroll
  for (int i = 0; i < 8; ++i) o[i] = p[i];
}
__device__ __forceinline__ void store4e(float* p, float a, float b, float c, float d) {
  p[0] = a; p[1] = b; p[2] = c; p[3] = d;
}

// ---------- setup: row norms, u=1, cost=0, fp16 copies of X,Y ----------
__global__ __launch_bounds__(256) void setup_kernel(
    const float* __restrict__ X, const float* __restrict__ Y,
    float* __restrict__ x2, float* __restrict__ y2,
    float* __restrict__ u, float* __restrict__ cost,
    h16* __restrict__ Xh, h16* __restrict__ Yh) {
  const int gid  = blockIdx.x * blockDim.x + threadIdx.x;
  const int wid  = gid >> 6;          // 0..16383 : one wave per row
  const int lane = threadIdx.x & 63;
  const bool isX = wid < Nn;
  const int row  = isX ? wid : wid - Nn;
  const float4* rp = (const float4*)((isX ? X : Y) + (size_t)row * Kd);
  float4 q = rp[lane];                // 64 lanes x float4 = 256 floats
  h16x4 hq; hq[0] = (h16)q.x; hq[1] = (h16)q.y; hq[2] = (h16)q.z; hq[3] = (h16)q.w;
  *(h16x4*)((isX ? Xh : Yh) + (size_t)row * Kd + lane * 4) = hq;
  float s = q.x*q.x + q.y*q.y + q.z*q.z + q.w*q.w;
#pragma unroll
  for (int o = 32; o > 0; o >>= 1) s += __shfl_down(s, o);
  if (lane == 0) { if (isX) x2[row] = s; else y2[row] = s; }
  if (gid < Mm) u[gid] = 1.0f;        // g0 = 0  ->  u0 = 1
  if (gid == 0) cost[0] = 0.0f;
}

// ---------- build K = exp(-C/LAM) as fp8 e4m3 via MFMA f16, 128x128 tile ----------
__global__ __launch_bounds__(256) void build_e8_mfma(
    const h16* __restrict__ Xh, const h16* __restrict__ Yh,
    const float* __restrict__ x2, const float* __restrict__ y2,
    uint8_t* __restrict__ E8) {
  __shared__ h16 smem[16384];         // 32 KB: A/B staging; epilogue reuses first 16 KB as fp8 tile
  __shared__ float x2s[128], y2s[128];
  const int tid = threadIdx.x;
  const int i0 = blockIdx.y * 128, j0 = blockIdx.x * 128;
  if (tid < 128) x2s[tid] = x2[i0 + tid];
  else           y2s[tid - 128] = y2[j0 + tid - 128];

  f32x16 acc[2][2];
#pragma unroll
  for (int a = 0; a < 2; ++a)
#pragma unroll
    for (int b = 0; b < 2; ++b)
#pragma unroll
      for (int r = 0; r < 16; ++r) acc[a][b][r] = 0.0f;

  const int w = tid >> 6, lane = tid & 63;
  const int mt0 = (w >> 1) * 2, nt0 = (w & 1) * 2;

  for (int kc = 0; kc < 4; ++kc) {                   // K = 256 in 4 chunks of 64
    __syncthreads();
#pragma unroll
    for (int p = 0; p < 4; ++p) {                    // stage 128 rows x 64 k (A and B), swizzled
      const int c  = p * 256 + tid;
      const int r  = c >> 3, k8 = c & 7;
      const int mt = r >> 5, m = r & 31, s = k8 >> 1, hf = k8 & 1;
      const int slot = (mt * 4 + s) * 64 + hf * 32 + (m ^ k8);
      *(uint4*)(smem + slot * 8)        = *(const uint4*)(Xh + (size_t)(i0 + r) * Kd + kc * 64 + k8 * 8);
      *(uint4*)(smem + 8192 + slot * 8) = *(const uint4*)(Yh + (size_t)(j0 + r) * Kd + kc * 64 + k8 * 8);
    }
    __syncthreads();
#pragma unroll
    for (int s = 0; s < 4; ++s) {                    // 4 k-steps of 16
      f16x8 a0 = *(const f16x8*)(smem + frag_slot(mt0,     s, lane) * 8);
      f16x8 a1 = *(const f16x8*)(smem + frag_slot(mt0 + 1, s, lane) * 8);
      f16x8 b0 = *(const f16x8*)(smem + 8192 + frag_slot(nt0,     s, lane) * 8);
      f16x8 b1 = *(const f16x8*)(smem + 8192 + frag_slot(nt0 + 1, s, lane) * 8);
      acc[0][0] = __builtin_amdgcn_mfma_f32_32x32x16_f16(a0, b0, acc[0][0], 0, 0, 0);
      acc[0][1] = __builtin_amdgcn_mfma_f32_32x32x16_f16(a0, b1, acc[0][1], 0, 0, 0);
      acc[1][0] = __builtin_amdgcn_mfma_f32_32x32x16_f16(a1, b0, acc[1][0], 0, 0, 0);
      acc[1][1] = __builtin_amdgcn_mfma_f32_32x32x16_f16(a1, b1, acc[1][1], 0, 0, 0);
    }
  }

  __syncthreads();                                   // all waves done reading A/B
  uint8_t* tile8 = (uint8_t*)smem;                   // 128x128 fp8 tile (16 KB)
  const int mq = (w >> 1) * 64, nq = (w & 1) * 64;
#pragma unroll
  for (int ti = 0; ti < 2; ++ti)
#pragma unroll
    for (int tj = 0; tj < 2; ++tj) {
      const int colb = nq + tj * 32 + (lane & 31);
      const float yv = y2s[colb];
#pragma unroll
      for (int r = 0; r < 16; ++r) {
        // 32x32 C/D layout: col = lane&31, row = (r&3) + 8*(r>>2) + 4*(lane>>5)
        const int rowb = mq + ti * 32 + (r & 3) + 8 * (r >> 2) + 4 * (lane >> 5);
        float sq = x2s[rowb] + yv - 2.0f * acc[ti][tj][r];
        float cc = sqrtf(fmaxf(sq, 0.0f) + 1e-6f);
        tile8[rowb * 128 + colb] = enc1_fp8(__expf(-0.1f * cc));
      }
    }
  __syncthreads();
#pragma unroll
  for (int p = 0; p < 4; ++p) {                      // coalesced 16B stores: 1024 chunks
    const int c = p * 256 + tid;                     // 128 rows x 8 chunks of 16B
    const int r = c >> 3, k = c & 7;
    *(uint4*)(E8 + (size_t)(i0 + r) * Mm + j0 + k * 16) = *(const uint4*)(tile8 + r * 128 + k * 16);
  }
}

// ---------- COOPERATIVE fused 50-iteration Sinkhorn loop ----------
// 1024 blocks x 256 threads, exactly co-resident (32 KB LDS -> 4 blocks/CU).
// Per iteration: row phase (2 rows/wave) -> grid.sync -> col phase
// (4 cols/thread x 64-row chunk) -> grid.sync -> combine (32-lane groups)
// -> grid.sync.  Memory patterns identical to the proven split kernels.
__global__ __launch_bounds__(256, 4) void sinkhorn_loop(
    const uint8_t* __restrict__ E8, float* __restrict__ u,
    float* __restrict__ v, float* __restrict__ part) {
  cg::grid_group grid = cg::this_grid();
  __shared__ float us[8192];                         // 32 KB staged u
  const int tid  = threadIdx.x;
  const int b    = blockIdx.x;
  const int lane = tid & 63;
  // row-phase mapping
  const int wid = (b * 256 + tid) >> 6;              // 0..4095
  const int r0r = wid * 2;
  const uint8_t* rowp = E8 + (size_t)r0r * Mm;
  // col-phase mapping: 1024 blocks = 8 col-groups x 128 row-chunks
  const int bx = b & 7, by = b >> 3;
  const int cc0 = bx * 1024 + tid * 4;               // 4 cols/thread
  const int cr0 = by * 64;                           // 64-row chunk
  const uint8_t* cbase = E8 + (size_t)cr0 * Mm + cc0;
  // combine mapping: 8 cols/block, one 32-lane group per col
  const int ju  = b * 8 + (tid >> 5);
  const int l32 = tid & 31;

  for (int it = 0; it < 50; ++it) {
    // ---- row phase: v_r = (1/n) / sum_j E_rj u_j ----
#pragma unroll
    for (int i = 0; i < 8; ++i) {
      const int o = (i * 256 + tid) * 4;
      *(float4*)(us + o) = *(const float4*)(u + o);
    }
    __syncthreads();
    float s0 = 0.0f, s1 = 0.0f;
#pragma unroll 1
    for (int g = 0; g < 8; g += 2) {                 // 4 E loads in flight
      const int ja = (g * 64 + lane) * 16;
      const int jb = ((g + 1) * 64 + lane) * 16;
      uint4 qa0 = *(const uint4*)(rowp + ja);
      uint4 qa1 = *(const uint4*)(rowp + (size_t)Mm + ja);
      uint4 qb0 = *(const uint4*)(rowp + jb);
      uint4 qb1 = *(const uint4*)(rowp + (size_t)Mm + jb);
      const uint32_t wa0[4] = {qa0.x, qa0.y, qa0.z, qa0.w};
      const uint32_t wa1[4] = {qa1.x, qa1.y, qa1.z, qa1.w};
      const uint32_t wb0[4] = {qb0.x, qb0.y, qb0.z, qb0.w};
      const uint32_t wb1[4] = {qb1.x, qb1.y, qb1.z, qb1.w};
#pragma unroll
      for (int d = 0; d < 4; ++d) {
        float f0[4], f1[4];
        const float4 uv = *(const float4*)(us + ja + d * 4);
        const float up[4] = {uv.x, uv.y, uv.z, uv.w};
        cvt4_fp8(wa0[d], f0); cvt4_fp8(wa1[d], f1);
#pragma unroll
        for (int i = 0; i < 4; ++i) { s0 = fmaf(f0[i], up[i], s0); s1 = fmaf(f1[i], up[i], s1); }
      }
#pragma unroll
      for (int d = 0; d < 4; ++d) {
        float f0[4], f1[4];
        const float4 uv = *(const float4*)(us + jb + d * 4);
        const float up[4] = {uv.x, uv.y, uv.z, uv.w};
        cvt4_fp8(wb0[d], f0); cvt4_fp8(wb1[d], f1);
#pragma unroll
        for (int i = 0; i < 4; ++i) { s0 = fmaf(f0[i], up[i], s0); s1 = fmaf(f1[i], up[i], s1); }
      }
    }
#pragma unroll
    for (int o = 32; o > 0; o >>= 1) { s0 += __shfl_down(s0, o); s1 += __shfl_down(s1, o); }
    if (lane == 0) *(float2*)(v + r0r) = make_float2(INV_N_F / s0, INV_N_F / s1);
    grid.sync();

    // ---- col phase: part[chunk][j] = sum_{rows in chunk} E_ij v_i ----
    float acc[4] = {};
#pragma unroll 1
    for (int rb = 0; rb < 64; rb += 8) {             // 8 rows batched
      uint32_t q[8];
#pragma unroll
      for (int r = 0; r < 8; ++r) q[r] = *(const uint32_t*)(cbase + (size_t)(rb + r) * Mm);
#pragma unroll
      for (int r = 0; r < 8; ++r) {
        const float vr = v[cr0 + rb + r];            // wave-uniform -> scalar load
        float f[4]; cvt4_fp8(q[r], f);
#pragma unroll
        for (int i = 0; i < 4; ++i) acc[i] = fmaf(f[i], vr, acc[i]);
      }
    }
    *(float4*)(part + (size_t)by * Mm + cc0) = make_float4(acc[0], acc[1], acc[2], acc[3]);
    grid.sync();

    // ---- combine: u_j = (1/m) / sum_chunks part ----
    float t = 0.0f;
#pragma unroll
    for (int k = 0; k < 4; ++k) t += part[(size_t)(l32 * 4 + k) * Mm + ju];
#pragma unroll
    for (int o = 16; o > 0; o >>= 1) t += __shfl_down(t, o, 32);
    if (l32 == 0) u[ju] = INV_N_F / t;
    grid.sync();
  }
}

// ---------- fallback split-loop kernels (used if coop launch fails) ----------
__global__ __launch_bounds__(256) void row_pass8_kernel(
    const uint8_t* __restrict__ E8, const float* __restrict__ u, float* __restrict__ v) {
  __shared__ float us[8192];
#pragma unroll
  for (int i = 0; i < 8; ++i) {
    const int o = (i * 256 + threadIdx.x) * 4;
    *(float4*)(us + o) = *(const float4*)(u + o);
  }
  __syncthreads();
  const int wid  = (blockIdx.x * blockDim.x + threadIdx.x) >> 6;
  const int lane = threadIdx.x & 63;
  const int r0   = wid * 2;
  const uint8_t* row = E8 + (size_t)r0 * Mm;
  float s0 = 0.0f, s1 = 0.0f;
#pragma unroll 1
  for (int g = 0; g < 8; g += 2) {
    const int ja = (g * 64 + lane) * 16;
    const int jb = ((g + 1) * 64 + lane) * 16;
    uint4 qa0 = *(const uint4*)(row + ja);
    uint4 qa1 = *(const uint4*)(row + (size_t)Mm + ja);
    uint4 qb0 = *(const uint4*)(row + jb);
    uint4 qb1 = *(const uint4*)(row + (size_t)Mm + jb);
    const uint32_t wa0[4] = {qa0.x, qa0.y, qa0.z, qa0.w};
    const uint32_t wa1[4] = {qa1.x, qa1.y, qa1.z, qa1.w};
    const uint32_t wb0[4] = {qb0.x, qb0.y, qb0.z, qb0.w};
    const uint32_t wb1[4] = {qb1.x, qb1.y, qb1.z, qb1.w};
#pragma unroll
    for (int d = 0; d < 4; ++d) {
      float f0[4], f1[4];
      const float4 uv = *(const float4*)(us + ja + d * 4);
      const float up[4] = {uv.x, uv.y, uv.z, uv.w};
      cvt4_fp8(wa0[d], f0); cvt4_fp8(wa1[d], f1);
#pragma unroll
      for (int i = 0; i < 4; ++i) { s0 = fmaf(f0[i], up[i], s0); s1 = fmaf(f1[i], up[i], s1); }
    }
#pragma unroll
    for (int d = 0; d < 4; ++d) {
      float f0[4], f1[4];
      const float4 uv = *(const float4*)(us + jb + d * 4);
      const float up[4] = {uv.x, uv.y, uv.z, uv.w};
      cvt4_fp8(wb0[d], f0); cvt4_fp8(wb1[d], f1);
#pragma unroll
      for (int i = 0; i < 4; ++i) { s0 = fmaf(f0[i], up[i], s0); s1 = fmaf(f1[i], up[i], s1); }
    }
  }
#pragma unroll
  for (int o = 32; o > 0; o >>= 1) { s0 += __shfl_down(s0, o); s1 += __shfl_down(s1, o); }
  if (lane == 0) *(float2*)(v + r0) = make_float2(INV_N_F / s0, INV_N_F / s1);
}

__global__ __launch_bounds__(256) void col_pass8_kernel(
    const uint8_t* __restrict__ E8, const float* __restrict__ v, float* __restrict__ part) {
  const int c0 = blockIdx.x * 4096 + threadIdx.x * 16;
  const int r0 = blockIdx.y * 64;
  const uint8_t* base = E8 + (size_t)r0 * Mm + c0;
  float acc[16] = {};
#pragma unroll 1
  for (int rb = 0; rb < 64; rb += 8) {
    uint4 q[8];
#pragma unroll
    for (int r = 0; r < 8; ++r) q[r] = *(const uint4*)(base + (size_t)(rb + r) * Mm);
#pragma unroll
    for (int r = 0; r < 8; ++r) {
      const float vr = v[r0 + rb + r];
      const uint32_t wd[4] = {q[r].x, q[r].y, q[r].z, q[r].w};
#pragma unroll
      for (int d = 0; d < 4; ++d) {
        float f[4]; cvt4_fp8(wd[d], f);
#pragma unroll
        for (int i = 0; i < 4; ++i) acc[d * 4 + i] = fmaf(f[i], vr, acc[d * 4 + i]);
      }
    }
  }
  float* dst = part + (size_t)blockIdx.y * Mm + c0;
#pragma unroll
  for (int d = 0; d < 4; ++d)
    *((float4*)dst + d) = make_float4(acc[d*4], acc[d*4+1], acc[d*4+2], acc[d*4+3]);
}

__global__ __launch_bounds__(256) void combine_kernel(
    const float* __restrict__ part, float* __restrict__ u) {
  const int j = blockIdx.x * blockDim.x + threadIdx.x;
  float t = 0.0f;
#pragma unroll 8
  for (int c = 0; c < 128; ++c) t += part[(size_t)c * Mm + j];
  u[j] = INV_N_F / t;
}

// ---------- FAST final: recompute C via MFMA; pi via two 32-KB half-tiles ----------
__global__ __launch_bounds__(256, 4) void final_mfma(
    const h16* __restrict__ Xh, const h16* __restrict__ Yh,
    const float* __restrict__ x2, const float* __restrict__ y2,
    const float* __restrict__ v, const float* __restrict__ u,
    float* __restrict__ pi, float* __restrict__ cost) {
  __shared__ __align__(16) unsigned char smemraw[32768];   // staging (32 KB) / half out-tile (32 KB)
  h16*   smem = (h16*)smemraw;
  float* tile = (float*)smemraw;                           // [64][128] f32
  __shared__ float x2s[128], y2s[128], vs[128], us[128];
  const int tid = threadIdx.x;
  const int i0 = blockIdx.y * 128, j0 = blockIdx.x * 128;
  if (tid < 128) { x2s[tid] = x2[i0 + tid]; vs[tid] = v[i0 + tid]; }
  else           { y2s[tid - 128] = y2[j0 + tid - 128]; us[tid - 128] = u[j0 + tid - 128]; }

  f32x16 acc[2][2];
#pragma unroll
  for (int a = 0; a < 2; ++a)
#pragma unroll
    for (int b = 0; b < 2; ++b)
#pragma unroll
      for (int r = 0; r < 16; ++r) acc[a][b][r] = 0.0f;

  const int w = tid >> 6, lane = tid & 63;
  const int mt0 = (w >> 1) * 2, nt0 = (w & 1) * 2;

  for (int kc = 0; kc < 4; ++kc) {
    __syncthreads();
#pragma unroll
    for (int p = 0; p < 4; ++p) {                    // swizzled staging (conflict-free)
      const int c  = p * 256 + tid;
      const int r  = c >> 3, k8 = c & 7;
      const int mt = r >> 5, m = r & 31, s = k8 >> 1, hf = k8 & 1;
      const int slot = (mt * 4 + s) * 64 + hf * 32 + (m ^ k8);
      *(uint4*)(smem + slot * 8)        = *(const uint4*)(Xh + (size_t)(i0 + r) * Kd + kc * 64 + k8 * 8);
      *(uint4*)(smem + 8192 + slot * 8) = *(const uint4*)(Yh + (size_t)(j0 + r) * Kd + kc * 64 + k8 * 8);
    }
    __syncthreads();
#pragma unroll
    for (int s = 0; s < 4; ++s) {
      f16x8 a0 = *(const f16x8*)(smem + frag_slot(mt0,     s, lane) * 8);
      f16x8 a1 = *(const f16x8*)(smem + frag_slot(mt0 + 1, s, lane) * 8);
      f16x8 b0 = *(const f16x8*)(smem + 8192 + frag_slot(nt0,     s, lane) * 8);
      f16x8 b1 = *(const f16x8*)(smem + 8192 + frag_slot(nt0 + 1, s, lane) * 8);
      acc[0][0] = __builtin_amdgcn_mfma_f32_32x32x16_f16(a0, b0, acc[0][0], 0, 0, 0);
      acc[0][1] = __builtin_amdgcn_mfma_f32_32x32x16_f16(a0, b1, acc[0][1], 0, 0, 0);
      acc[1][0] = __builtin_amdgcn_mfma_f32_32x32x16_f16(a1, b0, acc[1][0], 0, 0, 0);
      acc[1][1] = __builtin_amdgcn_mfma_f32_32x32x16_f16(a1, b1, acc[1][1], 0, 0, 0);
    }
  }

  __syncthreads();                                   // all staging reads done
  const int nq = (w & 1) * 64;
  float csum = 0.0f;
#pragma unroll
  for (int h = 0; h < 2; ++h) {                      // half h = rows h*64 .. h*64+63
    if ((w >> 1) == h) {                             // waves owning this half fill the tile
#pragma unroll
      for (int ti = 0; ti < 2; ++ti)
#pragma unroll
        for (int tj = 0; tj < 2; ++tj) {
          const int colb = nq + tj * 32 + (lane & 31);
          const float yv = y2s[colb], uu = us[colb];
#pragma unroll
          for (int r = 0; r < 16; ++r) {
            const int rl = ti * 32 + (r & 3) + 8 * (r >> 2) + 4 * (lane >> 5);  // local row 0..63
            float sq = x2s[h * 64 + rl] + yv - 2.0f * acc[ti][tj][r];
            float cc = sqrtf(fmaxf(sq, 0.0f) + 1e-6f);
            float p  = vs[h * 64 + rl] * __expf(-0.1f * cc) * uu;
            tile[rl * 128 + colb] = p;               // bank = colb%32 -> conflict-free
            csum = fmaf(p, cc, csum);
          }
        }
    }
    __syncthreads();
#pragma unroll
    for (int it2 = 0; it2 < 8; ++it2) {              // 2048 chunks of 16B = 64 rows x 512B
      const int c = it2 * 256 + tid;
      const int r = c >> 5, k = c & 31;
      *(uint4*)(pi + (size_t)(i0 + h * 64 + r) * Mm + j0 + k * 4) = *(const uint4*)(tile + r * 128 + k * 4);
    }
    __syncthreads();
  }
#pragma unroll
  for (int o = 32; o > 0; o >>= 1) csum += __shfl_down(csum, o);
  if (lane == 0) atomicAdd(cost, csum);
}

// ================= fp32 fallback path (ws too small), unchanged ==================
template <typename ET>
__global__ __launch_bounds__(256) void build_e_f32(
    const float* __restrict__ X, const float* __restrict__ Y,
    const float* __restrict__ x2, const float* __restrict__ y2,
    ET* __restrict__ E) {
  __shared__ float As[64][66];
  __shared__ float Bs[64][66];
  const int tid = threadIdx.x;
  const int tx = tid & 15;
  const int ty = tid >> 4;
  const int i0 = blockIdx.y * 64;
  const int j0 = blockIdx.x * 64;
  float acc[4][4] = {};
  for (int k0 = 0; k0 < Kd; k0 += 64) {
    __syncthreads();
#pragma unroll
    for (int rep = 0; rep < 16; ++rep) {
      const int e = rep * 256 + tid;
      const int k = e & 63, i = e >> 6;
      As[k][i] = X[(size_t)(i0 + i) * Kd + k0 + k];
      Bs[k][i] = Y[(size_t)(j0 + i) * Kd + k0 + k];
    }
    __syncthreads();
    for (int k = 0; k < 64; ++k) {
      float a0 = As[k][ty*4+0], a1 = As[k][ty*4+1], a2 = As[k][ty*4+2], a3 = As[k][ty*4+3];
      float b0 = Bs[k][tx*4+0], b1 = Bs[k][tx*4+1], b2 = Bs[k][tx*4+2], b3 = Bs[k][tx*4+3];
      acc[0][0] += a0*b0; acc[0][1] += a0*b1; acc[0][2] += a0*b2; acc[0][3] += a0*b3;
      acc[1][0] += a1*b0; acc[1][1] += a1*b1; acc[1][2] += a1*b2; acc[1][3] += a1*b3;
      acc[2][0] += a2*b0; acc[2][1] += a2*b1; acc[2][2] += a2*b2; acc[2][3] += a2*b3;
      acc[3][0] += a3*b0; acc[3][1] += a3*b1; acc[3][2] += a3*b2; acc[3][3] += a3*b3;
    }
  }
  float xx[4], yy[4];
#pragma unroll
  for (int d = 0; d < 4; ++d) { xx[d] = x2[i0 + ty*4 + d]; yy[d] = y2[j0 + tx*4 + d]; }
#pragma unroll
  for (int di = 0; di < 4; ++di) {
    float e4[4];
#pragma unroll
    for (int dj = 0; dj < 4; ++dj) {
      float sq = xx[di] + yy[dj] - 2.0f * acc[di][dj];
      float c  = sqrtf(fmaxf(sq, 0.0f) + 1e-6f);
      e4[dj] = __expf(-c * 0.1f);
    }
    store4e(&E[(size_t)(i0 + ty*4 + di) * Mm + j0 + tx*4], e4[0], e4[1], e4[2], e4[3]);
  }
}

template <typename ET>
__global__ __launch_bounds__(256) void row_pass_kernel(
    const ET* __restrict__ E, const float* __restrict__ u, float* __restrict__ v) {
  const int wid  = (blockIdx.x * blockDim.x + threadIdx.x) >> 6;
  const int lane = threadIdx.x & 63;
  const ET* row = E + (size_t)wid * Mm;
  float s = 0.0f;
#pragma unroll 4
  for (int g = 0; g < 16; ++g) {
    const int j8 = (g * 64 + lane) * 8;
    float ev[8]; load8(row + j8, ev);
    const float4 u0 = *(const float4*)(u + j8);
    const float4 u1 = *(const float4*)(u + j8 + 4);
    s += ev[0]*u0.x + ev[1]*u0.y + ev[2]*u0.z + ev[3]*u0.w;
    s += ev[4]*u1.x + ev[5]*u1.y + ev[6]*u1.z + ev[7]*u1.w;
  }
#pragma unroll
  for (int o = 32; o > 0; o >>= 1) s += __shfl_down(s, o);
  if (lane == 0) v[wid] = INV_N_F / s;
}

template <typename ET>
__global__ __launch_bounds__(256) void col_pass_kernel(
    const ET* __restrict__ E, const float* __restrict__ v, float* __restrict__ part) {
  const int c0 = blockIdx.x * 2048 + threadIdx.x * 8;
  const int r0 = blockIdx.y * 64;
  float acc[8] = {};
#pragma unroll 4
  for (int r = r0; r < r0 + 64; ++r) {
    const float vr = v[r];
    float ev[8]; load8(E + (size_t)r * Mm + c0, ev);
#pragma unroll
    for (int c = 0; c < 8; ++c) acc[c] += ev[c] * vr;
  }
  float* dst = part + (size_t)blockIdx.y * Mm + c0;
  *(float4*)dst       = make_float4(acc[0], acc[1], acc[2], acc[3]);
  *((float4*)dst + 1) = make_float4(acc[4], acc[5], acc[6], acc[7]);
}

template <typename ET>
__global__ __launch_bounds__(256) void final_pass_kernel(
    const ET* E, const float* __restrict__ v, const float* __restrict__ u,
    float* pi, float* cost) {            // E/pi alias in fallback -> no restrict
  const int wid  = (blockIdx.x * blockDim.x + threadIdx.x) >> 6;
  const int lane = threadIdx.x & 63;
  const ET* row = E + (size_t)wid * Mm;
  float* prow = pi + (size_t)wid * Mm;
  const float vi = v[wid];
  float csum = 0.0f;
  for (int g = 0; g < 16; ++g) {
    const int j8 = (g * 64 + lane) * 8;
    float ev[8]; load8(row + j8, ev);
#pragma unroll
    for (int c = 0; c < 8; ++c) {
      const float uu  = u[j8 + c];
      const float p   = vi * ev[c] * uu;
      const float Cij = -LAM_F * __logf(ev[c]);
      prow[j8 + c] = p;
      csum += p * Cij;
    }
  }
#pragma unroll
  for (int o = 32; o > 0; o >>= 1) csum += __shfl_down(csum, o);
  if (lane == 0) atomicAdd(cost, csum);
}

// ---------- host ----------
extern "C" void kernel_launch(void* const* d_in, const int* in_sizes, int n_in,
                              void* d_out, int out_size, void* d_ws, size_t ws_size,
                              hipStream_t stream) {
  const float* X = (const float*)d_in[0];
  const float* Y = (const float*)d_in[1];
  float* out  = (float*)d_out;
  float* cost = out;
  float* pi   = out + 1;

  char*  ws   = (char*)d_ws;
  float* x2   = (float*)ws;
  float* y2   = x2 + Nn;
  float* u    = y2 + Mm;
  float* v    = u + Mm;
  float* part = v + Nn;                                   // 128 x 8192 f32 = 4 MB
  h16*   XhW  = (h16*)(part + (size_t)128 * Mm);          // fp16 X copy (4 MB) - fast path
  h16*   YhW  = XhW + (size_t)Nn * Kd;                    // fp16 Y copy (4 MB)
  const size_t pre_bytes = (size_t)((char*)(YhW + (size_t)Mm * Kd) - ws);
  const size_t e_off = (pre_bytes + 255) & ~(size_t)255;
  const bool fast = ws_size >= e_off + (size_t)Nn * Mm + 256;   // + 64 MB fp8 E

  // Xh/Yh live in ws on fast path (final_mfma reads them while writing pi);
  // fallback parks them in the pi region (never read there).
  h16* Xh = fast ? XhW : (h16*)(((uintptr_t)pi + 15) & ~(uintptr_t)15);
  h16* Yh = Xh + (size_t)Nn * Kd;

  setup_kernel<<<4096, 256, 0, stream>>>(X, Y, x2, y2, u, cost, Xh, Yh);

  if (fast) {
    uint8_t* E8 = (uint8_t*)ws + e_off;                   // fp8 K (64 MB, L3-resident)
    build_e8_mfma<<<dim3(64, 64), 256, 0, stream>>>(Xh, Yh, x2, y2, E8);
    void* cargs[] = {(void*)&E8, (void*)&u, (void*)&v, (void*)&part};
    hipError_t ce = hipLaunchCooperativeKernel(
        (const void*)sinkhorn_loop, dim3(1024), dim3(256), cargs, 0, stream);
    if (ce != hipSuccess) {                               // fallback: proven split loop
      for (int it = 0; it < 50; ++it) {
        row_pass8_kernel<<<1024, 256, 0, stream>>>(E8, u, v);
        col_pass8_kernel<<<dim3(2, 128), 256, 0, stream>>>(E8, v, part);
        combine_kernel<<<32, 256, 0, stream>>>(part, u);
      }
    }
    final_mfma<<<dim3(64, 64), 256, 0, stream>>>(Xh, Yh, x2, y2, v, u, pi, cost);
  } else {
    float* E = pi;                                        // fallback: fp32 K parked in pi slot
    build_e_f32<float><<<dim3(128, 128), 256, 0, stream>>>(X, Y, x2, y2, E);
    for (int it = 0; it < 50; ++it) {
      row_pass_kernel<float><<<2048, 256, 0, stream>>>(E, u, v);
      col_pass_kernel<float><<<dim3(4, 128), 256, 0, stream>>>(E, v, part);
      combine_kernel<<<32, 256, 0, stream>>>(part, u);
    }
    final_pass_kernel<float><<<2048, 256, 0, stream>>>(E, v, u, pi, cost);  // in-place
  }
}